// Round 1
// baseline (63857.373 us; speedup 1.0000x reference)
//
#include <hip/hip_runtime.h>
#include <math.h>

#define H 1024
#define BATCH 512
#define KSTEPS 96

// ---------------------------------------------------------------------------
// Workspace layout (floats):
//   wct: [2 blobs][4 gates][H i][H j]  (transposed combined weights, j contiguous)
//        blob 0 (step 1, x==0):   g0=Whh_r, g1=Whh_z, g2=0,      g3=Whh_n
//        blob 1 (steps>=2, x==h): g0=Wih_r+Whh_r, g1=Wih_z+Whh_z, g2=Wih_n, g3=Whh_n
//   bc:  [4][H] fused biases (same for both blobs):
//        bc0=b_ih_r+b_hh_r, bc1=b_ih_z+b_hh_z, bc2=b_ih_n, bc3=b_hh_n
// ---------------------------------------------------------------------------

// Build WcT via LDS-tiled transpose. Grid: (H/32, H/32, 8), z = s*4+g. 256 thr.
__global__ void prep_wct(const float* __restrict__ wih,
                         const float* __restrict__ whh,
                         float* __restrict__ wct)
{
    __shared__ float t[32][36];
    const int z = blockIdx.z;
    const int s = z >> 2, g = z & 3;
    const long i0 = blockIdx.x * 32;
    const long j0 = blockIdx.y * 32;
    const int tid = threadIdx.x;

    const float* s1 = nullptr;
    const float* s2 = nullptr;
    if (s == 1) {
        if (g == 0)      { s1 = wih;             s2 = whh; }
        else if (g == 1) { s1 = wih + (long)H*H; s2 = whh + (long)H*H; }
        else if (g == 2) { s1 = wih + 2L*H*H; }
        else             { s1 = whh + 2L*H*H; }
    } else {
        if (g == 0)      { s1 = whh; }
        else if (g == 1) { s1 = whh + (long)H*H; }
        else if (g == 2) { /* zeros */ }
        else             { s1 = whh + 2L*H*H; }
    }

    // read coalesced over i (source contiguous dim)
    const int jl = tid >> 3;      // 0..31 source row (j)
    const int i4 = tid & 7;       // f4 chunk over i
    float4 v = make_float4(0.f, 0.f, 0.f, 0.f);
    if (s1) {
        v = *(const float4*)(s1 + (j0 + jl)*H + i0 + 4*i4);
        if (s2) {
            float4 w = *(const float4*)(s2 + (j0 + jl)*H + i0 + 4*i4);
            v.x += w.x; v.y += w.y; v.z += w.z; v.w += w.w;
        }
    }
    t[jl][4*i4+0] = v.x; t[jl][4*i4+1] = v.y;
    t[jl][4*i4+2] = v.z; t[jl][4*i4+3] = v.w;
    __syncthreads();

    // write coalesced over j (dest contiguous dim)
    const int il = tid >> 3;      // 0..31 dest row (i)
    const int j4 = tid & 7;       // f4 chunk over j
    float4 o;
    o.x = t[4*j4+0][il]; o.y = t[4*j4+1][il];
    o.z = t[4*j4+2][il]; o.w = t[4*j4+3][il];
    *(float4*)(wct + ((long)z*H + i0 + il)*H + j0 + 4*j4) = o;
}

// Fused biases. Grid: 4 blocks x 1024 threads.
__global__ void prep_bc(const float* __restrict__ bih,
                        const float* __restrict__ bhh,
                        float* __restrict__ bc)
{
    const int g = blockIdx.x;
    const int j = threadIdx.x;
    float v;
    if (g == 0)      v = bih[j]       + bhh[j];
    else if (g == 1) v = bih[H + j]   + bhh[H + j];
    else if (g == 2) v = bih[2*H + j];
    else             v = bhh[2*H + j];
    bc[g*H + j] = v;
}

// ---------------------------------------------------------------------------
// One GRU step: out[m][j] gates = h @ WcT + bc, then gate math.
// Tile: BM=32 batch rows x BJ=64 hidden cols, 256 threads, K-chunk 32,
// double-buffered LDS, one barrier per chunk (issue-early / write-late).
// Grid: (BATCH/32=16, H/64=16).
// ---------------------------------------------------------------------------
__global__ __launch_bounds__(256) void gru_step(
    const float* __restrict__ hprev, long hstride,
    const float* __restrict__ wct,   // one blob [4][H][H] (g,i,j)
    const float* __restrict__ bc,    // [4][H]
    float* __restrict__ hout, long ostride)
{
    __shared__ float ws[2][4][32][64];  // 64 KiB  (g, i_local, j_local)
    __shared__ float hs[2][32][36];     // 9 KiB   (m_local, i_local; +4 pad)

    const int tid = threadIdx.x;
    const int tx = tid & 15;            // j quad: j_local = 4*tx..4*tx+3
    const int ty = tid >> 4;            // m pair: m_local = 2*ty, 2*ty+1
    const long m0 = blockIdx.x * 32;
    const long j0 = blockIdx.y * 64;

    float acc[2][4][4] = {};            // [mm][gate][jj]

    // staging assignment
    const int hm  = tid >> 3;           // h row (0..31)
    const int hi4 = tid & 7;            // h f4 over i

    // ---- prologue: stage chunk 0 into buffer 0 ----
    float4 wreg[8];
    float4 hreg;
    #pragma unroll
    for (int qq = 0; qq < 8; ++qq) {
        const int f  = qq*256 + tid;            // 0..2047
        const int g  = f >> 9;
        const int il = (f >> 4) & 31;
        const int j4 = f & 15;
        wreg[qq] = *(const float4*)(wct + ((long)g*H + il)*H + j0 + 4*j4);
    }
    hreg = *(const float4*)(hprev + (m0 + hm)*hstride + 4*hi4);

    #pragma unroll
    for (int qq = 0; qq < 8; ++qq) {
        const int f  = qq*256 + tid;
        const int g  = f >> 9;
        const int il = (f >> 4) & 31;
        const int j4 = f & 15;
        *(float4*)&ws[0][g][il][4*j4] = wreg[qq];
    }
    *(float4*)&hs[0][hm][4*hi4] = hreg;
    __syncthreads();

    // ---- main loop over 32 K-chunks ----
    #pragma unroll 1
    for (int t = 0; t < 32; ++t) {
        const int cb = t & 1;

        // issue next chunk's global loads early (latency hides under compute)
        float4 wnext[8];
        float4 hnext;
        if (t < 31) {
            const long i0n = (long)(t + 1) * 32;
            #pragma unroll
            for (int qq = 0; qq < 8; ++qq) {
                const int f  = qq*256 + tid;
                const int g  = f >> 9;
                const int il = (f >> 4) & 31;
                const int j4 = f & 15;
                wnext[qq] = *(const float4*)(wct + ((long)g*H + i0n + il)*H + j0 + 4*j4);
            }
            hnext = *(const float4*)(hprev + (m0 + hm)*hstride + i0n + 4*hi4);
        }

        // compute current chunk
        #pragma unroll
        for (int kk = 0; kk < 32; ++kk) {
            const float h0 = hs[cb][2*ty + 0][kk];
            const float h1 = hs[cb][2*ty + 1][kk];
            #pragma unroll
            for (int g = 0; g < 4; ++g) {
                const float4 wv = *(const float4*)&ws[cb][g][kk][4*tx];
                acc[0][g][0] = fmaf(h0, wv.x, acc[0][g][0]);
                acc[0][g][1] = fmaf(h0, wv.y, acc[0][g][1]);
                acc[0][g][2] = fmaf(h0, wv.z, acc[0][g][2]);
                acc[0][g][3] = fmaf(h0, wv.w, acc[0][g][3]);
                acc[1][g][0] = fmaf(h1, wv.x, acc[1][g][0]);
                acc[1][g][1] = fmaf(h1, wv.y, acc[1][g][1]);
                acc[1][g][2] = fmaf(h1, wv.z, acc[1][g][2]);
                acc[1][g][3] = fmaf(h1, wv.w, acc[1][g][3]);
            }
        }

        // write next chunk into the other buffer (safe: it was last read in
        // iteration t-1, which completed at the previous barrier)
        if (t < 31) {
            const int nb = cb ^ 1;
            #pragma unroll
            for (int qq = 0; qq < 8; ++qq) {
                const int f  = qq*256 + tid;
                const int g  = f >> 9;
                const int il = (f >> 4) & 31;
                const int j4 = f & 15;
                *(float4*)&ws[nb][g][il][4*j4] = wnext[qq];
            }
            *(float4*)&hs[nb][hm][4*hi4] = hnext;
        }
        __syncthreads();
    }

    // ---- epilogue: gate math + store ----
    const float4 b0 = *(const float4*)(bc + 0*H + j0 + 4*tx);
    const float4 b1 = *(const float4*)(bc + 1*H + j0 + 4*tx);
    const float4 b2 = *(const float4*)(bc + 2*H + j0 + 4*tx);
    const float4 b3 = *(const float4*)(bc + 3*H + j0 + 4*tx);

    #pragma unroll
    for (int mm = 0; mm < 2; ++mm) {
        const long row = m0 + 2*ty + mm;
        const float4 hp = *(const float4*)(hprev + row*hstride + j0 + 4*tx);
        const float bb0[4] = {b0.x, b0.y, b0.z, b0.w};
        const float bb1[4] = {b1.x, b1.y, b1.z, b1.w};
        const float bb2[4] = {b2.x, b2.y, b2.z, b2.w};
        const float bb3[4] = {b3.x, b3.y, b3.z, b3.w};
        const float hh[4]  = {hp.x, hp.y, hp.z, hp.w};
        float o[4];
        #pragma unroll
        for (int d = 0; d < 4; ++d) {
            const float ar  = acc[mm][0][d] + bb0[d];
            const float az  = acc[mm][1][d] + bb1[d];
            const float in_ = acc[mm][2][d] + bb2[d];
            const float hn  = acc[mm][3][d] + bb3[d];
            const float r = 1.f / (1.f + expf(-ar));
            const float z = 1.f / (1.f + expf(-az));
            const float n = tanhf(fmaf(r, hn, in_));
            o[d] = n + z * (hh[d] - n);     // (1-z)*n + z*h
        }
        float4 ov = make_float4(o[0], o[1], o[2], o[3]);
        *(float4*)(hout + row*ostride + j0 + 4*tx) = ov;
    }
}

// ---------------------------------------------------------------------------
extern "C" void kernel_launch(void* const* d_in, const int* in_sizes, int n_in,
                              void* d_out, int out_size, void* d_ws, size_t ws_size,
                              hipStream_t stream)
{
    const float* c   = (const float*)d_in[0];
    // d_in[1] = K (scalar on device) — fixed at 96 per problem definition
    const float* wih = (const float*)d_in[2];
    const float* whh = (const float*)d_in[3];
    const float* bih = (const float*)d_in[4];
    const float* bhh = (const float*)d_in[5];
    float* out = (float*)d_out;

    float* wct = (float*)d_ws;              // [2][4][H][H]
    float* bc  = wct + 2L*4*H*H;            // [4][H]

    prep_wct<<<dim3(H/32, H/32, 8), 256, 0, stream>>>(wih, whh, wct);
    prep_bc<<<dim3(4), 1024, 0, stream>>>(bih, bhh, bc);

    const dim3 grid(BATCH/32, H/64), blk(256);
    const long ostride = (long)KSTEPS * H;
    for (int k = 0; k < KSTEPS; ++k) {
        const float* hprev = (k == 0) ? c : (out + (long)(k-1)*H);
        const long hstride = (k == 0) ? (long)H : ostride;
        const float* w     = (k == 0) ? wct : (wct + 4L*H*H);  // blob0 / blob1
        gru_step<<<grid, blk, 0, stream>>>(hprev, hstride, w, bc,
                                           out + (long)k*H, ostride);
    }
}

// Round 2
// 7736.175 us; speedup vs baseline: 8.2544x; 8.2544x over previous
//
#include <hip/hip_runtime.h>
#include <math.h>

#define H 1024
#define BATCH 512
#define KSTEPS 96
#define KH ((long)KSTEPS * H)

// async global->LDS, 16B per lane; dst must be wave-uniform base (lane*16 added by HW)
__device__ __forceinline__ void glds16(const float* g, float* l) {
    __builtin_amdgcn_global_load_lds(
        (const __attribute__((address_space(1))) void*)g,
        (__attribute__((address_space(3))) void*)l, 16, 0, 0);
}

// ---------------------------------------------------------------------------
// Workspace (floats):
//   wct: [2 blobs][4 gates][H k][H j]   transposed combined weights
//        blob0 (step 1, x==0):  g0=Whh_r, g1=Whh_z, g2=0, g3=Whh_n
//        blob1 (x==h):          g0=Wih_r+Whh_r, g1=Wih_z+Whh_z, g2=Wih_n, g3=Whh_n
//   bc:  [4][H] fused biases
//   G:   [4][BATCH][H] raw gate pre-activations (per step scratch)
//   hT:  [H][BATCH] transposed current hidden state
// ---------------------------------------------------------------------------

__global__ void prep_wct(const float* __restrict__ wih,
                         const float* __restrict__ whh,
                         float* __restrict__ wct)
{
    __shared__ float t[32][36];
    const int z = blockIdx.z;
    const int s = z >> 2, g = z & 3;
    const long i0 = blockIdx.x * 32;
    const long j0 = blockIdx.y * 32;
    const int tid = threadIdx.x;

    const float* s1 = nullptr;
    const float* s2 = nullptr;
    if (s == 1) {
        if (g == 0)      { s1 = wih;             s2 = whh; }
        else if (g == 1) { s1 = wih + (long)H*H; s2 = whh + (long)H*H; }
        else if (g == 2) { s1 = wih + 2L*H*H; }
        else             { s1 = whh + 2L*H*H; }
    } else {
        if (g == 0)      { s1 = whh; }
        else if (g == 1) { s1 = whh + (long)H*H; }
        else if (g == 2) { /* zeros */ }
        else             { s1 = whh + 2L*H*H; }
    }

    const int jl = tid >> 3;
    const int i4 = tid & 7;
    float4 v = make_float4(0.f, 0.f, 0.f, 0.f);
    if (s1) {
        v = *(const float4*)(s1 + (j0 + jl)*H + i0 + 4*i4);
        if (s2) {
            float4 w = *(const float4*)(s2 + (j0 + jl)*H + i0 + 4*i4);
            v.x += w.x; v.y += w.y; v.z += w.z; v.w += w.w;
        }
    }
    t[jl][4*i4+0] = v.x; t[jl][4*i4+1] = v.y;
    t[jl][4*i4+2] = v.z; t[jl][4*i4+3] = v.w;
    __syncthreads();

    const int il = tid >> 3;
    const int j4 = tid & 7;
    float4 o;
    o.x = t[4*j4+0][il]; o.y = t[4*j4+1][il];
    o.z = t[4*j4+2][il]; o.w = t[4*j4+3][il];
    *(float4*)(wct + ((long)z*H + i0 + il)*H + j0 + 4*j4) = o;
}

__global__ void prep_bc(const float* __restrict__ bih,
                        const float* __restrict__ bhh,
                        float* __restrict__ bc)
{
    const int g = blockIdx.x;
    const int j = threadIdx.x;
    float v;
    if (g == 0)      v = bih[j]       + bhh[j];
    else if (g == 1) v = bih[H + j]   + bhh[H + j];
    else if (g == 2) v = bih[2*H + j];
    else             v = bhh[2*H + j];
    bc[g*H + j] = v;
}

// c [BATCH][H] -> hT [H][BATCH], 64x64 tiles. grid (8,16), 256 thr.
__global__ __launch_bounds__(256) void tr_c(const float* __restrict__ c,
                                            float* __restrict__ hT)
{
    __shared__ float tmp[64][68];
    const int tid = threadIdx.x;
    const int tx = tid & 15;
    const int ty = tid >> 4;
    const long m0 = blockIdx.x * 64;
    const long j0 = blockIdx.y * 64;

    #pragma unroll
    for (int mm = 0; mm < 4; ++mm) {
        const long m = m0 + 4*ty + mm;
        const float4 v = *(const float4*)(c + m*H + j0 + 4*tx);
        tmp[4*tx+0][4*ty+mm] = v.x;
        tmp[4*tx+1][4*ty+mm] = v.y;
        tmp[4*tx+2][4*ty+mm] = v.z;
        tmp[4*tx+3][4*ty+mm] = v.w;
    }
    __syncthreads();
    #pragma unroll
    for (int mm = 0; mm < 4; ++mm) {
        const int r = 4*ty + mm;
        const float4 v = *(const float4*)&tmp[r][4*tx];
        *(float4*)(hT + (j0 + r)*BATCH + m0 + 4*tx) = v;
    }
}

// ---------------------------------------------------------------------------
// GEMM: G[g][m][j] = sum_k hT[k][m] * wblob[g][k][j], for g in {2bg, 2bg+1}.
// Block: 64 m x 64 j x 2 gates. 256 thr: tx(16)->4j, ty(16)->4m.
// K-chunks of 32, double-buffered LDS staged via global_load_lds (no VGPRs).
// grid (8, 16, 2) = 256 blocks.
// ---------------------------------------------------------------------------
__global__ __launch_bounds__(256) void gru_gemm(
    const float* __restrict__ wblob,   // [4][H][H] (this blob)
    const float* __restrict__ hT,      // [H][BATCH]
    float* __restrict__ G)             // [4][BATCH][H]
{
    __shared__ float ws[2][2][32][64];  // 32 KiB  (buf, gate, k, j)
    __shared__ float hs[2][32][64];     // 16 KiB  (buf, k, m)

    const int tid = threadIdx.x;
    const int tx = tid & 15;
    const int ty = tid >> 4;
    const int wv = tid >> 6;            // wave id (0..3), uniform per wave
    const long m0 = blockIdx.x * 64;
    const long j0 = blockIdx.y * 64;
    const int g0 = blockIdx.z * 2;

    const float* wbase = wblob + (long)g0 * H * H;

    float4 acc[4][2];                   // [mm][gate], float4 over j
    #pragma unroll
    for (int mm = 0; mm < 4; ++mm)
        #pragma unroll
        for (int gg = 0; gg < 2; ++gg)
            acc[mm][gg] = make_float4(0.f, 0.f, 0.f, 0.f);

    // stage K-chunk t into buffer buf (async; completes at next barrier)
    auto stage = [&](int t, int buf) {
        const long k0 = (long)t * 32;
        // weights: 2 gates x 32 k x 16 f4(j) = 1024 f4 slots
        #pragma unroll
        for (int q = 0; q < 4; ++q) {
            const int s  = q*256 + tid;
            const int gg = s >> 9;
            const int kk = (s >> 4) & 31;
            const int j4 = s & 15;
            const float* src = wbase + ((long)gg*H + k0 + kk)*H + j0 + 4*j4;
            float* dst = &ws[buf][0][0][0] + (q*1024 + wv*256);
            glds16(src, dst);
        }
        // hT: 32 k x 16 f4(m) = 512 f4 slots
        #pragma unroll
        for (int q = 0; q < 2; ++q) {
            const int s  = q*256 + tid;
            const int kk = s >> 4;
            const int m4 = s & 15;
            const float* src = hT + (k0 + kk)*BATCH + m0 + 4*m4;
            float* dst = &hs[buf][0][0] + (q*1024 + wv*256);
            glds16(src, dst);
        }
    };

    stage(0, 0);
    __syncthreads();   // drains vmcnt before barrier (compiler-emitted)

    #pragma unroll 1
    for (int t = 0; t < 32; ++t) {
        const int cb = t & 1;
        if (t < 31) stage(t + 1, cb ^ 1);   // issue early; lands by next barrier

        #pragma unroll
        for (int kk = 0; kk < 32; ++kk) {
            const float4 hv = *(const float4*)&hs[cb][kk][4*ty];   // 4 m (bcast over tx)
            const float4 w0 = *(const float4*)&ws[cb][0][kk][4*tx];
            const float4 w1 = *(const float4*)&ws[cb][1][kk][4*tx];
            const float hm[4] = {hv.x, hv.y, hv.z, hv.w};
            #pragma unroll
            for (int mm = 0; mm < 4; ++mm) {
                acc[mm][0].x = fmaf(hm[mm], w0.x, acc[mm][0].x);
                acc[mm][0].y = fmaf(hm[mm], w0.y, acc[mm][0].y);
                acc[mm][0].z = fmaf(hm[mm], w0.z, acc[mm][0].z);
                acc[mm][0].w = fmaf(hm[mm], w0.w, acc[mm][0].w);
                acc[mm][1].x = fmaf(hm[mm], w1.x, acc[mm][1].x);
                acc[mm][1].y = fmaf(hm[mm], w1.y, acc[mm][1].y);
                acc[mm][1].z = fmaf(hm[mm], w1.z, acc[mm][1].z);
                acc[mm][1].w = fmaf(hm[mm], w1.w, acc[mm][1].w);
            }
        }
        __syncthreads();
    }

    #pragma unroll
    for (int gg = 0; gg < 2; ++gg)
        #pragma unroll
        for (int mm = 0; mm < 4; ++mm)
            *(float4*)(G + ((long)(g0+gg)*BATCH + m0 + 4*ty + mm)*H + j0 + 4*tx)
                = acc[mm][gg];
}

// ---------------------------------------------------------------------------
// Epilogue: gate math from G + biases, writes out[:,k,:] AND next hT.
// Block: 64 m x 64 j. grid (8,16), 256 thr.
// ---------------------------------------------------------------------------
__global__ __launch_bounds__(256) void gru_epi(
    const float* __restrict__ G,
    const float* __restrict__ hprev, long hstride,
    const float* __restrict__ bc,
    float* __restrict__ outk,          // out + k*H (row stride KH)
    float* __restrict__ hT)
{
    __shared__ float tmp[64][68];
    const int tid = threadIdx.x;
    const int tx = tid & 15;
    const int ty = tid >> 4;
    const long m0 = blockIdx.x * 64;
    const long j0 = blockIdx.y * 64;

    const float4 b0 = *(const float4*)(bc + 0*H + j0 + 4*tx);
    const float4 b1 = *(const float4*)(bc + 1*H + j0 + 4*tx);
    const float4 b2 = *(const float4*)(bc + 2*H + j0 + 4*tx);
    const float4 b3 = *(const float4*)(bc + 3*H + j0 + 4*tx);
    const float bb0[4] = {b0.x, b0.y, b0.z, b0.w};
    const float bb1[4] = {b1.x, b1.y, b1.z, b1.w};
    const float bb2[4] = {b2.x, b2.y, b2.z, b2.w};
    const float bb3[4] = {b3.x, b3.y, b3.z, b3.w};

    #pragma unroll
    for (int mm = 0; mm < 4; ++mm) {
        const long m = m0 + 4*ty + mm;
        const float4 g0v = *(const float4*)(G + (0L*BATCH + m)*H + j0 + 4*tx);
        const float4 g1v = *(const float4*)(G + (1L*BATCH + m)*H + j0 + 4*tx);
        const float4 g2v = *(const float4*)(G + (2L*BATCH + m)*H + j0 + 4*tx);
        const float4 g3v = *(const float4*)(G + (3L*BATCH + m)*H + j0 + 4*tx);
        const float4 hp  = *(const float4*)(hprev + m*hstride + j0 + 4*tx);
        const float ga[4] = {g0v.x, g0v.y, g0v.z, g0v.w};
        const float gb[4] = {g1v.x, g1v.y, g1v.z, g1v.w};
        const float gc[4] = {g2v.x, g2v.y, g2v.z, g2v.w};
        const float gd[4] = {g3v.x, g3v.y, g3v.z, g3v.w};
        const float hh[4] = {hp.x, hp.y, hp.z, hp.w};
        float o[4];
        #pragma unroll
        for (int d = 0; d < 4; ++d) {
            const float ar  = ga[d] + bb0[d];
            const float az  = gb[d] + bb1[d];
            const float in_ = gc[d] + bb2[d];
            const float hn  = gd[d] + bb3[d];
            const float r = 1.f / (1.f + expf(-ar));
            const float z = 1.f / (1.f + expf(-az));
            const float n = tanhf(fmaf(r, hn, in_));
            o[d] = n + z * (hh[d] - n);
        }
        *(float4*)(outk + m*KH + j0 + 4*tx) = make_float4(o[0], o[1], o[2], o[3]);
        tmp[4*tx+0][4*ty+mm] = o[0];
        tmp[4*tx+1][4*ty+mm] = o[1];
        tmp[4*tx+2][4*ty+mm] = o[2];
        tmp[4*tx+3][4*ty+mm] = o[3];
    }
    __syncthreads();
    #pragma unroll
    for (int mm = 0; mm < 4; ++mm) {
        const int r = 4*ty + mm;
        const float4 v = *(const float4*)&tmp[r][4*tx];
        *(float4*)(hT + (j0 + r)*BATCH + m0 + 4*tx) = v;
    }
}

// ---------------------------------------------------------------------------
extern "C" void kernel_launch(void* const* d_in, const int* in_sizes, int n_in,
                              void* d_out, int out_size, void* d_ws, size_t ws_size,
                              hipStream_t stream)
{
    const float* c   = (const float*)d_in[0];
    // d_in[1] = K (fixed 96)
    const float* wih = (const float*)d_in[2];
    const float* whh = (const float*)d_in[3];
    const float* bih = (const float*)d_in[4];
    const float* bhh = (const float*)d_in[5];
    float* out = (float*)d_out;

    float* wct = (float*)d_ws;                 // 2*4*H*H
    float* bc  = wct + 2L*4*H*H;               // 4*H
    float* G   = bc + 4L*H;                    // 4*BATCH*H
    float* hT  = G + 4L*BATCH*H;               // H*BATCH

    prep_wct<<<dim3(H/32, H/32, 8), 256, 0, stream>>>(wih, whh, wct);
    prep_bc<<<dim3(4), 1024, 0, stream>>>(bih, bhh, bc);
    tr_c<<<dim3(8, 16), 256, 0, stream>>>(c, hT);

    for (int k = 0; k < KSTEPS; ++k) {
        const float* wblob = (k == 0) ? wct : (wct + 4L*H*H);
        gru_gemm<<<dim3(8, 16, 2), 256, 0, stream>>>(wblob, hT, G);

        const float* hprev = (k == 0) ? c : (out + (long)(k-1)*H);
        const long hstride = (k == 0) ? (long)H : KH;
        gru_epi<<<dim3(8, 16), 256, 0, stream>>>(G, hprev, hstride, bc,
                                                 out + (long)k*H, hT);
    }
}

// Round 4
// 2333.031 us; speedup vs baseline: 27.3710x; 3.3159x over previous
//
#include <hip/hip_runtime.h>
#include <math.h>

#define H 1024
#define BATCH 512
#define KSTEPS 96
#define KH ((long)KSTEPS * H)

typedef __attribute__((ext_vector_type(8))) short short8;
typedef __attribute__((ext_vector_type(4))) float f32x4;

__device__ __forceinline__ unsigned short f2bf(float x) {
    union { float f; unsigned int u; } v; v.f = x;
    unsigned int r = v.u + 0x7fffu + ((v.u >> 16) & 1u);
    return (unsigned short)(r >> 16);
}
__device__ __forceinline__ float bf2f(unsigned short h) {
    union { unsigned int u; float f; } v; v.u = ((unsigned int)h) << 16;
    return v.f;
}

// async global->LDS 16B/lane; dst wave-uniform base (HW adds lane*16)
__device__ __forceinline__ void glds16(const void* g, void* l) {
    __builtin_amdgcn_global_load_lds(
        (const __attribute__((address_space(1))) void*)g,
        (__attribute__((address_space(3))) void*)l, 16, 0, 0);
}

// ---------------------------------------------------------------------------
// Workspace (bytes):
//   blob0, blob1 : each [32 t][64 by][2 s(hi/lo)][4 jf][4 kg][16 col][8 el] bf16
//                  (16.78 MB each) — MFMA-fragment-ordered combined weights.
//        blob0 (step 1, x==0): g0=Whh_r, g1=Whh_z, g2=0, g3=Whh_n
//        blob1 (x==h):  g0=Wih_r+Whh_r, g1=Wih_z+Whh_z, g2=Wih_n, g3=Whh_n
//        J = by*64 + jf*16 + col;  g = J&3; j = J>>2;  k = t*32 + kg*8 + el
//   bcJ  : [4096] f32, J-interleaved fused biases
//   hTa, hTb : each [32 t][4 bx][2 s][8 mf][4 kg][16 row][8 el] bf16 (2 MB)
//              fragment-ordered hidden state, double-buffered across steps
// ---------------------------------------------------------------------------

__global__ void prep_w(const float* __restrict__ wih,
                       const float* __restrict__ whh,
                       unsigned short* __restrict__ blob0,
                       unsigned short* __restrict__ blob1)
{
    const unsigned int f = blockIdx.x * 256 + threadIdx.x;  // 0..2^22-1
    const int el = f & 7;
    const int col = (f >> 3) & 15;
    const int kg = (f >> 7) & 3;
    const int jf = (f >> 9) & 3;
    const int by = (f >> 11) & 63;
    const int t  = (f >> 17) & 31;
    const int b  = blockIdx.y;      // blob select

    const int J = by * 64 + jf * 16 + col;
    const int g = J & 3;
    const long j = J >> 2;
    const long k = t * 32 + kg * 8 + el;

    float v = 0.f;
    if (b == 1) {
        if (g == 0)      v = wih[j*1024 + k]           + whh[j*1024 + k];
        else if (g == 1) v = wih[(1024+j)*1024 + k]    + whh[(1024+j)*1024 + k];
        else if (g == 2) v = wih[(2048+j)*1024 + k];
        else             v = whh[(2048+j)*1024 + k];
    } else {
        if (g == 0)      v = whh[j*1024 + k];
        else if (g == 1) v = whh[(1024+j)*1024 + k];
        else if (g == 2) v = 0.f;
        else             v = whh[(2048+j)*1024 + k];
    }
    const unsigned short hi = f2bf(v);
    const unsigned short lo = f2bf(v - bf2f(hi));

    unsigned short* blob = (b == 0) ? blob0 : blob1;
    const long base = ((long)(t*64 + by)*2) * 2048 + jf*512 + kg*128 + col*8 + el;
    blob[base]        = hi;
    blob[base + 2048] = lo;
}

__global__ void prep_bcJ(const float* __restrict__ bih,
                         const float* __restrict__ bhh,
                         float* __restrict__ bcJ)
{
    const int J = blockIdx.x * 256 + threadIdx.x;   // 0..4095
    const int g = J & 3;
    const int j = J >> 2;
    float v;
    if (g == 0)      v = bih[j]        + bhh[j];
    else if (g == 1) v = bih[1024 + j] + bhh[1024 + j];
    else if (g == 2) v = bih[2048 + j];
    else             v = bhh[2048 + j];
    bcJ[J] = v;
}

// c [512][1024] fp32 -> hT fragment layout (hi/lo bf16)
__global__ void prep_h0(const float* __restrict__ c,
                        unsigned short* __restrict__ hT)
{
    const int f = blockIdx.x * 256 + threadIdx.x;   // 0..65535
    const int ko = f & 127;
    const int m  = f >> 7;
    const long k0 = (long)ko * 8;
    const int t  = ko >> 2;
    const int kg = ko & 3;
    const int bx = m >> 7;
    const int mf = (m >> 4) & 7;
    const int row = m & 15;

    unsigned short hi[8], lo[8];
    #pragma unroll
    for (int e = 0; e < 8; ++e) {
        const float v = c[(long)m*1024 + k0 + e];
        hi[e] = f2bf(v);
        lo[e] = f2bf(v - bf2f(hi[e]));
    }
    const long base = ((long)(t*4 + bx)*2) * 4096 + mf*512 + kg*128 + row*8;
    #pragma unroll
    for (int e = 0; e < 8; ++e) { hT[base + e] = hi[e]; hT[base + 4096 + e] = lo[e]; }
}

// ---------------------------------------------------------------------------
// Fused GRU step. Grid 256 (1/CU), 256 threads (4 waves).
// Block tile: 128 m x 64 J (=16 j x 4 gates). Wave w: m_local [32w,32w+32).
// K-chunks of 32, double-buffered LDS via global_load_lds from
// fragment-ordered blobs. 3-product bf16 hi/lo split MFMA (fp32-accurate).
// Epilogue: LDS dump of C-frags -> per-lane gate math -> out + next hT.
// ---------------------------------------------------------------------------
__global__ __launch_bounds__(256) void gru_step(
    const unsigned short* __restrict__ wblob,  // fragment-ordered
    const unsigned short* __restrict__ hTr,    // read: current h frags
    unsigned short* __restrict__ hTw,          // write: next h frags
    const float* __restrict__ hprev, long hstride,
    const float* __restrict__ bcJ,
    float* __restrict__ outk)                  // out + k*H, row stride KH
{
    __shared__ __attribute__((aligned(16))) char smem[49152]; // 2 x 24KB

    const int tid  = threadIdx.x;
    const int lane = tid & 63;
    const int wv   = tid >> 6;

    // XCD-chunked decode: XCD x hosts by in [8x, 8x+8), all bx.
    const int id   = blockIdx.x;
    const int xcd  = id & 7;
    const int slot = id >> 3;
    const int by   = xcd * 8 + (slot & 7);   // 0..63  (J tile)
    const int bx   = slot >> 3;              // 0..3   (m tile)
    const long m0  = (long)bx * 128;

    const char* hsrc = (const char*)hTr + (long)bx * 16384;       // + t*4*16384
    const char* wsrc = (const char*)wblob + (long)by * 8192;      // + t*64*8192

    f32x4 acc[2][4];
    #pragma unroll
    for (int i = 0; i < 2; ++i)
        #pragma unroll
        for (int jf = 0; jf < 4; ++jf)
            acc[i][jf] = (f32x4){0.f, 0.f, 0.f, 0.f};

    // stage chunk t into buffer buf: h 16KB + w 8KB, 6 glds16/thread
    auto stage = [&](int t, int buf) {
        char* base = smem + buf * 24576;
        const char* hs = hsrc + (long)t * 65536;      // t*4*16384
        const char* ws = wsrc + (long)t * 524288;     // t*64*8192
        #pragma unroll
        for (int q = 0; q < 4; ++q) {
            const int seg = q * 4 + wv;
            glds16(hs + seg * 1024 + lane * 16, base + seg * 1024);
        }
        #pragma unroll
        for (int q = 0; q < 2; ++q) {
            const int seg = q * 4 + wv;
            glds16(ws + seg * 1024 + lane * 16, base + 16384 + seg * 1024);
        }
    };

    stage(0, 0);
    __syncthreads();

    #pragma unroll 1
    for (int t = 0; t < 32; ++t) {
        const int cb = t & 1;
        if (t < 31) stage(t + 1, cb ^ 1);

        const char* hb = smem + cb * 24576;
        const char* wb = hb + 16384;

        short8 ah[2], al[2];
        #pragma unroll
        for (int i = 0; i < 2; ++i) {
            const int mf = 2 * wv + i;
            ah[i] = *(const short8*)(hb + mf * 1024 + lane * 16);
            al[i] = *(const short8*)(hb + 8192 + mf * 1024 + lane * 16);
        }
        #pragma unroll
        for (int jf = 0; jf < 4; ++jf) {
            const short8 bh = *(const short8*)(wb + jf * 1024 + lane * 16);
            const short8 bl = *(const short8*)(wb + 4096 + jf * 1024 + lane * 16);
            #pragma unroll
            for (int i = 0; i < 2; ++i) {
                acc[i][jf] = __builtin_amdgcn_mfma_f32_16x16x32_bf16(ah[i], bh, acc[i][jf], 0, 0, 0);
                acc[i][jf] = __builtin_amdgcn_mfma_f32_16x16x32_bf16(al[i], bh, acc[i][jf], 0, 0, 0);
                acc[i][jf] = __builtin_amdgcn_mfma_f32_16x16x32_bf16(ah[i], bl, acc[i][jf], 0, 0, 0);
            }
        }
        __syncthreads();
    }

    // ---- fused epilogue ----
    float* D = (float*)(smem + wv * 4096);   // [16 row][64 J] per wave
    const int clo = lane & 15;               // C frag: col = lane&15
    const int chi = lane >> 4;               // rows (lane>>4)*4 + r

    #pragma unroll
    for (int mf = 0; mf < 2; ++mf) {
        #pragma unroll
        for (int jf = 0; jf < 4; ++jf)
            #pragma unroll
            for (int r = 0; r < 4; ++r)
                D[(chi * 4 + r) * 64 + jf * 16 + clo] = acc[mf][jf][r];
        __syncthreads();

        #pragma unroll
        for (int q = 0; q < 4; ++q) {
            const int row16 = q * 4 + chi;
            const int jj = clo;
            const float4 gv = *(const float4*)(D + row16 * 64 + jj * 4);
            const float4 bv = *(const float4*)(bcJ + by * 64 + jj * 4);
            const long m = m0 + wv * 32 + mf * 16 + row16;
            const long j = (long)by * 16 + jj;

            const float hp = hprev[m * hstride + j];
            const float rr = 1.f / (1.f + expf(-(gv.x + bv.x)));
            const float zz = 1.f / (1.f + expf(-(gv.y + bv.y)));
            const float nn = tanhf(gv.z + bv.z + rr * (gv.w + bv.w));
            const float o  = nn + zz * (hp - nn);

            outk[m * KH + j] = o;

            const unsigned short hi = f2bf(o);
            const unsigned short lo = f2bf(o - bf2f(hi));
            const int t2  = by >> 1;
            const int kg2 = (int)((j & 31) >> 3);
            const long hb = ((long)(t2*4 + bx)*2) * 4096
                          + (wv*2 + mf) * 512 + kg2 * 128 + (m & 15) * 8 + (jj & 7);
            hTw[hb]        = hi;
            hTw[hb + 4096] = lo;
        }
        __syncthreads();
    }
}

// ---------------------------------------------------------------------------
extern "C" void kernel_launch(void* const* d_in, const int* in_sizes, int n_in,
                              void* d_out, int out_size, void* d_ws, size_t ws_size,
                              hipStream_t stream)
{
    const float* c   = (const float*)d_in[0];
    // d_in[1] = K (fixed 96)
    const float* wih = (const float*)d_in[2];
    const float* whh = (const float*)d_in[3];
    const float* bih = (const float*)d_in[4];
    const float* bhh = (const float*)d_in[5];
    float* out = (float*)d_out;

    unsigned short* blob0 = (unsigned short*)d_ws;            // 8.39M ushort
    unsigned short* blob1 = blob0 + 8388608L;
    float*          bcJ   = (float*)(blob1 + 8388608L);       // 4096 f32
    unsigned short* hTa   = (unsigned short*)(bcJ + 4096);    // 1M ushort
    unsigned short* hTb   = hTa + 1048576L;

    prep_w  <<<dim3(16384, 2), 256, 0, stream>>>(wih, whh, blob0, blob1);
    prep_bcJ<<<dim3(16),       256, 0, stream>>>(bih, bhh, bcJ);
    prep_h0 <<<dim3(256),      256, 0, stream>>>(c, hTa);

    for (int k = 0; k < KSTEPS; ++k) {
        const unsigned short* wb  = (k == 0) ? blob0 : blob1;
        const unsigned short* hTr = (k & 1) ? hTb : hTa;
        unsigned short*       hTw = (k & 1) ? hTa : hTb;
        const float* hprev = (k == 0) ? c : (out + (long)(k - 1) * H);
        const long hstride = (k == 0) ? (long)H : KH;
        gru_step<<<dim3(256), 256, 0, stream>>>(wb, hTr, hTw, hprev, hstride,
                                                bcJ, out + (long)k * H);
    }
}

// Round 5
// 2304.231 us; speedup vs baseline: 27.7131x; 1.0125x over previous
//
#include <hip/hip_runtime.h>
#include <math.h>

#define H 1024
#define BATCH 512
#define KSTEPS 96
#define KH ((long)KSTEPS * H)

typedef __attribute__((ext_vector_type(8))) short short8;
typedef __attribute__((ext_vector_type(4))) float f32x4;

__device__ __forceinline__ unsigned short f2bf(float x) {
    union { float f; unsigned int u; } v; v.f = x;
    unsigned int r = v.u + 0x7fffu + ((v.u >> 16) & 1u);
    return (unsigned short)(r >> 16);
}
__device__ __forceinline__ float bf2f(unsigned short h) {
    union { unsigned int u; float f; } v; v.u = ((unsigned int)h) << 16;
    return v.f;
}

// async global->LDS 16B/lane; dst wave-uniform base (HW adds lane*16)
__device__ __forceinline__ void glds16(const void* g, void* l) {
    __builtin_amdgcn_global_load_lds(
        (const __attribute__((address_space(1))) void*)g,
        (__attribute__((address_space(3))) void*)l, 16, 0, 0);
}
#define MEMFENCE asm volatile("" ::: "memory")

// ---------------------------------------------------------------------------
// Workspace layouts identical to round 4 (blob0/blob1 fragment-ordered weights,
// bcJ J-interleaved biases, hTa/hTb fragment-ordered hidden state hi/lo).
// ---------------------------------------------------------------------------

__global__ void prep_w(const float* __restrict__ wih,
                       const float* __restrict__ whh,
                       unsigned short* __restrict__ blob0,
                       unsigned short* __restrict__ blob1)
{
    const unsigned int f = blockIdx.x * 256 + threadIdx.x;  // 0..2^22-1
    const int el = f & 7;
    const int col = (f >> 3) & 15;
    const int kg = (f >> 7) & 3;
    const int jf = (f >> 9) & 3;
    const int by = (f >> 11) & 63;
    const int t  = (f >> 17) & 31;
    const int b  = blockIdx.y;      // blob select

    const int J = by * 64 + jf * 16 + col;
    const int g = J & 3;
    const long j = J >> 2;
    const long k = t * 32 + kg * 8 + el;

    float v = 0.f;
    if (b == 1) {
        if (g == 0)      v = wih[j*1024 + k]           + whh[j*1024 + k];
        else if (g == 1) v = wih[(1024+j)*1024 + k]    + whh[(1024+j)*1024 + k];
        else if (g == 2) v = wih[(2048+j)*1024 + k];
        else             v = whh[(2048+j)*1024 + k];
    } else {
        if (g == 0)      v = whh[j*1024 + k];
        else if (g == 1) v = whh[(1024+j)*1024 + k];
        else if (g == 2) v = 0.f;
        else             v = whh[(2048+j)*1024 + k];
    }
    const unsigned short hi = f2bf(v);
    const unsigned short lo = f2bf(v - bf2f(hi));

    unsigned short* blob = (b == 0) ? blob0 : blob1;
    const long base = ((long)(t*64 + by)*2) * 2048 + jf*512 + kg*128 + col*8 + el;
    blob[base]        = hi;
    blob[base + 2048] = lo;
}

__global__ void prep_bcJ(const float* __restrict__ bih,
                         const float* __restrict__ bhh,
                         float* __restrict__ bcJ)
{
    const int J = blockIdx.x * 256 + threadIdx.x;   // 0..4095
    const int g = J & 3;
    const int j = J >> 2;
    float v;
    if (g == 0)      v = bih[j]        + bhh[j];
    else if (g == 1) v = bih[1024 + j] + bhh[1024 + j];
    else if (g == 2) v = bih[2048 + j];
    else             v = bhh[2048 + j];
    bcJ[J] = v;
}

// c [512][1024] fp32 -> hT fragment layout (hi/lo bf16)
__global__ void prep_h0(const float* __restrict__ c,
                        unsigned short* __restrict__ hT)
{
    const int f = blockIdx.x * 256 + threadIdx.x;   // 0..65535
    const int ko = f & 127;
    const int m  = f >> 7;
    const long k0 = (long)ko * 8;
    const int t  = ko >> 2;
    const int kg = ko & 3;
    const int bx = m >> 7;
    const int mf = (m >> 4) & 7;
    const int row = m & 15;

    unsigned short hi[8], lo[8];
    #pragma unroll
    for (int e = 0; e < 8; ++e) {
        const float v = c[(long)m*1024 + k0 + e];
        hi[e] = f2bf(v);
        lo[e] = f2bf(v - bf2f(hi[e]));
    }
    const long base = ((long)(t*4 + bx)*2) * 4096 + mf*512 + kg*128 + row*8;
    #pragma unroll
    for (int e = 0; e < 8; ++e) { hT[base + e] = hi[e]; hT[base + 4096 + e] = lo[e]; }
}

// ---------------------------------------------------------------------------
// Fused GRU step, counted-vmcnt pipeline.
// Grid 256 (1/CU), 256 threads (4 waves). Block: 128 m x 64 J.
// W double-buffered in LDS via glds16 (2/thread/chunk, issued 1 ahead).
// h (A-frags) loaded straight to VGPRs, prefetched 1 chunk ahead.
// Per-chunk sync: s_waitcnt vmcnt(4) (W landed, A still in flight) + raw
// s_barrier — staging loads stay in flight across the barrier (T4).
// ---------------------------------------------------------------------------
__global__ __launch_bounds__(256) void gru_step(
    const unsigned short* __restrict__ wblob,
    const unsigned short* __restrict__ hTr,
    unsigned short* __restrict__ hTw,
    const float* __restrict__ hprev, long hstride,
    const float* __restrict__ bcJ,
    float* __restrict__ outk)
{
    __shared__ __attribute__((aligned(16))) char smem[16384]; // 2 x 8KB W; epilogue D reuse

    const int tid  = threadIdx.x;
    const int lane = tid & 63;
    const int wv   = tid >> 6;

    const int id   = blockIdx.x;
    const int xcd  = id & 7;
    const int slot = id >> 3;
    const int by   = xcd * 8 + (slot & 7);   // 0..63  (J tile)
    const int bx   = slot >> 3;              // 0..3   (m tile)
    const long m0  = (long)bx * 128;

    const char* hbase = (const char*)hTr + (long)bx * 16384;   // + t*65536
    const char* wsrc  = (const char*)wblob + (long)by * 8192;  // + t*524288

    const int clo = lane & 15;
    const int chi = lane >> 4;

    // bias folded into accumulator init: C-frag col (lane&15) selects J
    f32x4 acc[2][4];
    #pragma unroll
    for (int jf = 0; jf < 4; ++jf) {
        const float b = bcJ[by * 64 + jf * 16 + clo];
        acc[0][jf] = (f32x4){b, b, b, b};
        acc[1][jf] = (f32x4){b, b, b, b};
    }

    auto stageW = [&](int t, char* base) {
        const char* ws = wsrc + (long)t * 524288;
        #pragma unroll
        for (int q = 0; q < 2; ++q) {
            const int seg = q * 4 + wv;
            glds16(ws + seg * 1024 + lane * 16, base + seg * 1024);
        }
    };
    auto loadA = [&](int t, short8& h0, short8& h1, short8& l0, short8& l1) {
        const char* hs = hbase + (long)t * 65536;
        h0 = *(const short8*)(hs + (2*wv + 0) * 1024 + lane * 16);
        h1 = *(const short8*)(hs + (2*wv + 1) * 1024 + lane * 16);
        l0 = *(const short8*)(hs + (8 + 2*wv + 0) * 1024 + lane * 16);
        l1 = *(const short8*)(hs + (8 + 2*wv + 1) * 1024 + lane * 16);
    };
    auto compute = [&](const char* wb, short8 ah0, short8 ah1,
                       short8 al0, short8 al1) {
        #pragma unroll
        for (int jf = 0; jf < 4; ++jf) {
            const short8 bh = *(const short8*)(wb + jf * 1024 + lane * 16);
            const short8 bl = *(const short8*)(wb + 4096 + jf * 1024 + lane * 16);
            acc[0][jf] = __builtin_amdgcn_mfma_f32_16x16x32_bf16(ah0, bh, acc[0][jf], 0, 0, 0);
            acc[0][jf] = __builtin_amdgcn_mfma_f32_16x16x32_bf16(al0, bh, acc[0][jf], 0, 0, 0);
            acc[0][jf] = __builtin_amdgcn_mfma_f32_16x16x32_bf16(ah0, bl, acc[0][jf], 0, 0, 0);
            acc[1][jf] = __builtin_amdgcn_mfma_f32_16x16x32_bf16(ah1, bh, acc[1][jf], 0, 0, 0);
            acc[1][jf] = __builtin_amdgcn_mfma_f32_16x16x32_bf16(al1, bh, acc[1][jf], 0, 0, 0);
            acc[1][jf] = __builtin_amdgcn_mfma_f32_16x16x32_bf16(ah1, bl, acc[1][jf], 0, 0, 0);
        }
    };

    short8 A0h0, A0h1, A0l0, A0l1;   // even-chunk A set
    short8 A1h0, A1h1, A1l0, A1l1;   // odd-chunk A set

    // ---- prologue: W(0) first (oldest in vmcnt FIFO), then A(0) ----
    stageW(0, smem);
    MEMFENCE;
    loadA(0, A0h0, A0h1, A0l0, A0l1);
    asm volatile("s_waitcnt vmcnt(4)" ::: "memory");   // W(0) landed; A(0) flying
    __builtin_amdgcn_s_barrier();

    #pragma unroll 1
    for (int tt = 0; tt < 16; ++tt) {
        // ---- even chunk t0 = 2tt (reads buf0, set0) ----
        {
            const int t = 2 * tt;                      // 0..30, always < 31
            stageW(t + 1, smem + 8192);                // W first
            MEMFENCE;
            loadA(t + 1, A1h0, A1h1, A1l0, A1l1);      // then A
            compute(smem, A0h0, A0h1, A0l0, A0l1);
            asm volatile("s_waitcnt vmcnt(4)" ::: "memory");  // W(t+1) landed
            __builtin_amdgcn_s_barrier();
        }
        // ---- odd chunk t1 = 2tt+1 (reads buf1, set1) ----
        {
            const int t = 2 * tt + 1;                  // 1..31
            if (tt < 15) {
                stageW(t + 1, smem);
                MEMFENCE;
                loadA(t + 1, A0h0, A0h1, A0l0, A0l1);
            }
            compute(smem + 8192, A1h0, A1h1, A1l0, A1l1);
            if (tt < 15) {
                asm volatile("s_waitcnt vmcnt(4)" ::: "memory");
                __builtin_amdgcn_s_barrier();
            }
        }
    }

    __syncthreads();   // full drain once; smem becomes epilogue scratch

    // ---- fused epilogue (bias already in acc) ----
    float* D = (float*)(smem + wv * 4096);   // [16 row][64 J] per wave

    #pragma unroll
    for (int mf = 0; mf < 2; ++mf) {
        #pragma unroll
        for (int jf = 0; jf < 4; ++jf)
            #pragma unroll
            for (int r = 0; r < 4; ++r)
                D[(chi * 4 + r) * 64 + jf * 16 + clo] = acc[mf][jf][r];
        __syncthreads();

        #pragma unroll
        for (int q = 0; q < 4; ++q) {
            const int row16 = q * 4 + chi;
            const int jj = clo;
            const float4 gv = *(const float4*)(D + row16 * 64 + jj * 4);
            const long m = m0 + wv * 32 + mf * 16 + row16;
            const long j = (long)by * 16 + jj;

            const float hp = hprev[m * hstride + j];
            const float rr = 1.f / (1.f + expf(-gv.x));
            const float zz = 1.f / (1.f + expf(-gv.y));
            const float nn = tanhf(fmaf(rr, gv.w, gv.z));
            const float o  = nn + zz * (hp - nn);

            outk[m * KH + j] = o;

            const unsigned short hi = f2bf(o);
            const unsigned short lo = f2bf(o - bf2f(hi));
            const int t2  = by >> 1;
            const int kg2 = (int)((j & 31) >> 3);
            const long hb = ((long)(t2*4 + bx)*2) * 4096
                          + (wv*2 + mf) * 512 + kg2 * 128 + (m & 15) * 8 + (jj & 7);
            hTw[hb]        = hi;
            hTw[hb + 4096] = lo;
        }
        __syncthreads();
    }
}

// ---------------------------------------------------------------------------
extern "C" void kernel_launch(void* const* d_in, const int* in_sizes, int n_in,
                              void* d_out, int out_size, void* d_ws, size_t ws_size,
                              hipStream_t stream)
{
    const float* c   = (const float*)d_in[0];
    // d_in[1] = K (fixed 96)
    const float* wih = (const float*)d_in[2];
    const float* whh = (const float*)d_in[3];
    const float* bih = (const float*)d_in[4];
    const float* bhh = (const float*)d_in[5];
    float* out = (float*)d_out;

    unsigned short* blob0 = (unsigned short*)d_ws;            // 8.39M ushort
    unsigned short* blob1 = blob0 + 8388608L;
    float*          bcJ   = (float*)(blob1 + 8388608L);       // 4096 f32
    unsigned short* hTa   = (unsigned short*)(bcJ + 4096);    // 1M ushort
    unsigned short* hTb   = hTa + 1048576L;

    prep_w  <<<dim3(16384, 2), 256, 0, stream>>>(wih, whh, blob0, blob1);
    prep_bcJ<<<dim3(16),       256, 0, stream>>>(bih, bhh, bcJ);
    prep_h0 <<<dim3(256),      256, 0, stream>>>(c, hTa);

    for (int k = 0; k < KSTEPS; ++k) {
        const unsigned short* wb  = (k == 0) ? blob0 : blob1;
        const unsigned short* hTr = (k & 1) ? hTb : hTa;
        unsigned short*       hTw = (k & 1) ? hTa : hTb;
        const float* hprev = (k == 0) ? c : (out + (long)(k - 1) * H);
        const long hstride = (k == 0) ? (long)H : KH;
        gru_step<<<dim3(256), 256, 0, stream>>>(wb, hTr, hTw, hprev, hstride,
                                                bcJ, out + (long)k * H);
    }
}